// Round 14
// baseline (138.770 us; speedup 1.0000x reference)
//
#include <hip/hip_runtime.h>

#define DIM 512
#define BATCH 65536
#define BM 32
#define THREADS 512
#define TILES 4
#define NBLK (BATCH / (BM * TILES))   // 512 blocks

typedef float f32x4 __attribute__((ext_vector_type(4)));
typedef float f32x16 __attribute__((ext_vector_type(16)));
typedef __bf16 bf16x8 __attribute__((ext_vector_type(8)));

__device__ __forceinline__ unsigned f2bf(float f) {
    unsigned u = __float_as_uint(f);
    return (u + 0x7FFFu + ((u >> 16) & 1u)) >> 16;
}

// LDS-only barrier (all barriers here guard LDS): no vmcnt drain, so loads
// issued before the barrier stay in flight across it (T14 enabler).
__device__ __forceinline__ void lbar() {
    asm volatile("s_waitcnt lgkmcnt(0)" ::: "memory");
    __builtin_amdgcn_s_barrier();
    __builtin_amdgcn_sched_barrier(0);
}

// Sf in MFMA-B-fragment order: Sf[((k0*16 + np)*64 + lane)*8 + j]
//   = bf16( A[n][k] + A[k][n] ),  n = np*32 + (lane&31),  k = k0*16 + (lane>>5)*8 + j
__global__ void prep_Sfrag(const float* __restrict__ A, unsigned short* __restrict__ Sf) {
    int idx = blockIdx.x * 256 + threadIdx.x;    // 0..32767 : (k0, np, lane)
    int lane = idx & 63;
    int np   = (idx >> 6) & 15;
    int k0   = idx >> 10;
    int n     = np * 32 + (lane & 31);
    int kbase = k0 * 16 + (lane >> 5) * 8;
    unsigned short tmp[8];
    #pragma unroll
    for (int j = 0; j < 8; ++j) {
        int k = kbase + j;
        tmp[j] = (unsigned short)f2bf(A[n * DIM + k] + A[k * DIM + n]);
    }
    *(uint4*)(Sf + (size_t)idx * 8) = *(const uint4*)tmp;
}

// out[b][0:512] = p[b] + q[b].S ; out[b][512:1024] = q[b]
// R9 phase-pipelined structure + two wait-chain reorders:
//  (1) khalf's first B-loads issue BEFORE the next phase's q-loads (vmcnt is
//      FIFO: q ahead of B would make B's wait drain q's ~900cyc HBM latency);
//  (2) epilogue p-loads issue BEFORE the acc->sc writes (cross one lbar,
//      latency hidden under LDS writes + barrier instead of fully exposed).
__global__ __launch_bounds__(THREADS, 4)
void gemm_kernel(const float* __restrict__ pq,
                 const unsigned short* __restrict__ Sf,
                 float* __restrict__ out) {
    __shared__ __align__(16) unsigned short qh[2][BM * 256];  // 2 x 16 KB bf16 half-K
    __shared__ float sc[BM * 256];                            // 32 KB epilogue scratch
    const int tid  = threadIdx.x;
    const int wid  = tid >> 6;
    const int lane = tid & 63;
    const int row  = lane & 31;
    const int khalf = lane >> 5;
    const int rb = blockIdx.x * (BM * TILES);
    const unsigned short* Sfp = Sf + ((size_t)(wid * 2) * 64 + lane) * 8;

    f32x4 stg[4];   // staged q for the next phase (consumed within one phase)

    auto issue_loads = [&](int ph) {
        int tile = ph >> 1, half = ph & 1;
        #pragma unroll
        for (int i = 0; i < 2; ++i) {
            int slot = i * THREADS + tid;
            int r = slot >> 5, c8 = slot & 31;
            size_t g = (size_t)(rb + tile * BM + r) * 1024 + 512 + half * 256 + c8 * 8;
            stg[2*i]   = __builtin_nontemporal_load((const f32x4*)(pq + g));
            stg[2*i+1] = __builtin_nontemporal_load((const f32x4*)(pq + g + 4));
        }
    };
    auto write_back = [&](int ph) {
        int tile = ph >> 1, half = ph & 1;
        unsigned short* dst = qh[ph & 1];
        #pragma unroll
        for (int i = 0; i < 2; ++i) {
            int slot = i * THREADS + tid;
            int r = slot >> 5, c8 = slot & 31;
            size_t g = (size_t)(rb + tile * BM + r) * 1024 + 512 + half * 256 + c8 * 8;
            __builtin_nontemporal_store(stg[2*i],   (f32x4*)(out + g));     // q passthrough
            __builtin_nontemporal_store(stg[2*i+1], (f32x4*)(out + g + 4));
            unsigned u0 = f2bf(stg[2*i].x)   | (f2bf(stg[2*i].y)   << 16);
            unsigned u1 = f2bf(stg[2*i].z)   | (f2bf(stg[2*i].w)   << 16);
            unsigned u2 = f2bf(stg[2*i+1].x) | (f2bf(stg[2*i+1].y) << 16);
            unsigned u3 = f2bf(stg[2*i+1].z) | (f2bf(stg[2*i+1].w) << 16);
            int b = r * 512 + ((c8 * 16) ^ ((r & 7) << 4));
            *(uint4*)((char*)dst + b) = make_uint4(u0, u1, u2, u3);
        }
    };
    // k-half loop; first two B fragments are passed in (issued before q-loads).
    auto khalf_loop = [&](int ph, f32x16& acc0, f32x16& acc1,
                          bf16x8 b0_c, bf16x8 b1_c) {
        int half = ph & 1;
        const unsigned short* buf = qh[ph & 1];
        const unsigned short* sp = Sfp + (size_t)(half * 16) * 8192;
        #pragma unroll
        for (int k = 0; k < 16; ++k) {
            bf16x8 b0_n, b1_n;
            if (k < 15) {
                b0_n = *(const bf16x8*)(sp + (size_t)(k + 1) * 8192);
                b1_n = *(const bf16x8*)(sp + (size_t)(k + 1) * 8192 + 512);
            }
            int b = row * 512 + ((k * 32 + khalf * 16) ^ ((row & 7) << 4));
            bf16x8 a = *(const bf16x8*)((const char*)buf + b);
            acc0 = __builtin_amdgcn_mfma_f32_32x32x16_bf16(a, b0_c, acc0, 0, 0, 0);
            acc1 = __builtin_amdgcn_mfma_f32_32x32x16_bf16(a, b1_c, acc1, 0, 0, 0);
            if (k < 15) { b0_c = b0_n; b1_c = b1_n; }
        }
    };
    auto epilogue = [&](int tile, const f32x16& acc0, const f32x16& acc1) {
        int tb = rb + tile * BM;
        #pragma unroll
        for (int pass = 0; pass < 2; ++pass) {
            const f32x16& ac = pass ? acc1 : acc0;
            // (2) p-loads first: in flight across the LDS writes + lbar
            f32x4 pv0, pv1, pv2, pv3;
            {
                int c0 = tid, c1 = tid + 512, c2 = tid + 1024, c3 = tid + 1536;
                #define PG(c) ((size_t)(tb + ((c) >> 6)) * 1024 + \
                               (((c) & 63) >> 3) * 64 + (((c) & 63) & 7) * 4 + pass * 32)
                pv0 = __builtin_nontemporal_load((const f32x4*)(pq + PG(c0)));
                pv1 = __builtin_nontemporal_load((const f32x4*)(pq + PG(c1)));
                pv2 = __builtin_nontemporal_load((const f32x4*)(pq + PG(c2)));
                pv3 = __builtin_nontemporal_load((const f32x4*)(pq + PG(c3)));
                #undef PG
            }
            #pragma unroll
            for (int reg = 0; reg < 16; ++reg) {
                int r = (reg & 3) + 8 * (reg >> 2) + 4 * khalf;
                sc[r * 256 + wid * 32 + row] = ac[reg];   // 2-way bank alias: free
            }
            lbar();
            #pragma unroll
            for (int j = 0; j < 4; ++j) {
                int c = tid + j * 512;
                int r = c >> 6, cc = c & 63;
                int gcol = (cc >> 3) * 64 + (cc & 7) * 4 + pass * 32;
                size_t g = (size_t)(tb + r) * 1024 + gcol;
                f32x4 v = *(const f32x4*)(sc + r * 256 + cc * 4);
                f32x4 pv = (j == 0) ? pv0 : (j == 1) ? pv1 : (j == 2) ? pv2 : pv3;
                __builtin_nontemporal_store(pv + v, (f32x4*)(out + g));
            }
            lbar();
        }
    };

    f32x16 acc0, acc1;
    // prologue: phase 0 synchronous
    issue_loads(0);
    write_back(0);
    lbar();

    for (int ph = 0; ph < 2 * TILES; ++ph) {
        if ((ph & 1) == 0) { acc0 = f32x16{}; acc1 = f32x16{}; }
        // (1) current khalf's first B-loads BEFORE next phase's q-loads
        const unsigned short* sp0 = Sfp + (size_t)((ph & 1) * 16) * 8192;
        bf16x8 b0_c = *(const bf16x8*)(sp0);
        bf16x8 b1_c = *(const bf16x8*)(sp0 + 512);
        if (ph + 1 < 2 * TILES) issue_loads(ph + 1);     // in flight across k-half
        khalf_loop(ph, acc0, acc1, b0_c, b1_c);
        if (ph + 1 < 2 * TILES) write_back(ph + 1);      // passthrough + LDS fill
        lbar();
        if (ph & 1) epilogue(ph >> 1, acc0, acc1);
    }
}

extern "C" void kernel_launch(void* const* d_in, const int* in_sizes, int n_in,
                              void* d_out, int out_size, void* d_ws, size_t ws_size,
                              hipStream_t stream) {
    const float* pq = (const float*)d_in[0];
    const float* A  = (const float*)d_in[1];
    float* out = (float*)d_out;
    unsigned short* Sf = (unsigned short*)d_ws;   // 512 KB fragment-ordered S

    prep_Sfrag<<<128, 256, 0, stream>>>(A, Sf);
    gemm_kernel<<<NBLK, THREADS, 0, stream>>>(pq, Sf, out);
}